// Round 1
// 61.132 us; speedup vs baseline: 1.0239x; 1.0239x over previous
//
#include <hip/hip_runtime.h>

// SC-based GEMM, strength-reduced, single fused dispatch with tile-local pack.
//
// out[m,n] = (1/256) * sum_k min(T1[m,k],T2[k,n]) * a1[m,k] * a2[k,n]
// T = min(floor(|x|*2^(s+8)), 256),  a = sign(x)*2^-s,
// s = clip(floor(-log2|x|),0,8)  (x==0 -> T=0 kills the term).
//
// R4: occupancy fix. Previous version was 256 blocks x 256 thr = 1 wave/SIMD
// (zero latency hiding; every LDS/global/shuffle dependency stalled the lone
// wave). Now 256 blocks x 1024 thr = 16 waves/block = 4 waves/SIMD; K is
// split 4-way across waves (wk = w>>2), reduced via 2 cheap ds_swizzle
// butterfly steps + a 16-slice LDS reduction. Same total work, 4x hiding,
// 4x shorter per-thread critical path.

constexpr int DIM = 256;
constexpr int PAD = 257;            // float2 row stride: hot LDS reads <=2-way

__device__ inline float2 pack2(float v) {
    float ax = fabsf(v);
    int   E;
    float fm = frexpf(ax, &E);          // ax = fm*2^E, fm in [0.5,1); frexp(0)=(0,0)
    int s = (fm == 0.5f ? 1 : 0) - E;   // floor(-log2 ax)
    s = s < 0 ? 0 : (s > 8 ? 8 : s);    // clip to [0, DATA_WIDTH]  (v_med3)
    float tf = floorf(ldexpf(ax, s + 8));   // floor(|x| * 2^s * 256), exact
    tf = fminf(tf, 256.0f);                 // unary popcount saturates at L=256
    float af = ldexpf(copysignf(1.0f, v), -s);  // sign * 2^-s (x==0: tf=0, dead)
    return make_float2(tf, af);
}

__global__ __launch_bounds__(1024, 4) void scgemm_fused(
    const float* __restrict__ x1, const float* __restrict__ x2,
    float* __restrict__ out)
{
    __shared__ float2 sP1[16 * PAD];     // [mi][k]   (T,a) of x1 tile rows
    __shared__ float2 sP2[16 * PAD];     // [nj][k]   (T,a) of x2 tile cols (transposed)
    __shared__ float4 red4[16][16][4];   // [wk*4+ksg][mi][njg]  16 KB partials

    const int t  = threadIdx.x;
    const int w  = t >> 6;               // wave 0..15
    const int l  = t & 63;
    const int m0 = (blockIdx.x >> 4) * 16;
    const int n0 = (blockIdx.x & 15) * 16;

    // ---- pack x1 tile: 16 rows x 256 k; wave w covers cols [16w,16w+16) ----
    {
        const int r  = l >> 2;                       // row 0..15
        const int c0 = w * 16 + (l & 3) * 4;         // 4-col segment
        float4 q = *(const float4*)(x1 + (m0 + r) * DIM + c0);
        float v[4] = {q.x, q.y, q.z, q.w};
        #pragma unroll
        for (int j = 0; j < 4; ++j) {
            int cc = (j + r) & 3;                    // rotate: spreads banks
            sP1[r * PAD + c0 + cc] = pack2(v[cc]);
        }
    }
    // ---- pack x2 tile: 256 k x 16 n, stored k-contiguous (transposed) ----
    {
        const int k = t >> 2;                        // k 0..255
        const int q = t & 3;                         // nj segment
        float4 w4 = *(const float4*)(x2 + k * DIM + n0 + q * 4);
        float vv[4] = {w4.x, w4.y, w4.z, w4.w};
        #pragma unroll
        for (int jj = 0; jj < 4; ++jj) {
            int cc = (jj + k) & 3;                   // rotate: spreads banks
            sP2[(q * 4 + cc) * PAD + k] = pack2(vv[cc]);
        }
    }
    __syncthreads();

    // ---- register-blocked min-GEMM ----
    // wave: wm = w&3 -> mi rows 4wm..4wm+3;  wk = w>>2 -> k quarter [64wk,64wk+64)
    // lane: njg = l&3 -> nj cols 4njg..;     ks = l>>2 -> k sub-slice
    const int wm  = w & 3;
    const int wk  = w >> 2;
    const int njg = l & 3;
    const int ks  = l >> 2;

    const float2* b1 = sP1 + (wm * 4) * PAD + wk * 64 + ks;
    const float2* b2 = sP2 + (njg * 4) * PAD + wk * 64 + ks;

    float acc[4][4] = {};
    #pragma unroll
    for (int j = 0; j < 4; ++j) {                    // k = 64wk + ks + 16j
        float2 p1[4], p2[4];
        #pragma unroll
        for (int i = 0; i < 4; ++i)   p1[i]  = b1[i * PAD + 16 * j];   // bcast
        #pragma unroll
        for (int jj = 0; jj < 4; ++jj) p2[jj] = b2[jj * PAD + 16 * j]; // 2-way
        #pragma unroll
        for (int i = 0; i < 4; ++i)
            #pragma unroll
            for (int jj = 0; jj < 4; ++jj)
                acc[i][jj] = fmaf(fminf(p1[i].x, p2[jj].x),
                                  p1[i].y * p2[jj].y, acc[i][jj]);
    }

    // ---- reduce ks bits 0,1 (lane bits 2,3): two cheap in-32 swizzles ----
    #pragma unroll
    for (int mask = 4; mask <= 8; mask <<= 1)
        #pragma unroll
        for (int i = 0; i < 4; ++i)
            #pragma unroll
            for (int jj = 0; jj < 4; ++jj)
                acc[i][jj] += __shfl_xor(acc[i][jj], mask, 64);

    // lanes with bits 2,3 clear hold sums over ks in {4*ksg .. 4*ksg+3}
    if ((l & 12) == 0) {
        const int ksg = l >> 4;                      // lane bits 4,5
        #pragma unroll
        for (int i = 0; i < 4; ++i)
            red4[wk * 4 + ksg][wm * 4 + i][njg] =
                make_float4(acc[i][0], acc[i][1], acc[i][2], acc[i][3]);
    }
    __syncthreads();

    // ---- final 16-slice sum + store (coalesced, threads 0..255) ----
    if (t < 256) {
        const int mi = t >> 4;
        const int nj = t & 15;
        const float* rp = (const float*)red4;
        float s = 0.f;
        #pragma unroll
        for (int g = 0; g < 16; ++g)
            s += rp[(g * 16 + mi) * 16 + nj];
        out[(m0 + mi) * DIM + n0 + nj] = s * (1.0f / 256.0f);
    }
}

extern "C" void kernel_launch(void* const* d_in, const int* in_sizes, int n_in,
                              void* d_out, int out_size, void* d_ws, size_t ws_size,
                              hipStream_t stream)
{
    const float* x1  = (const float*)d_in[0];   // tensor_1 [256,256] f32
    const float* x2  = (const float*)d_in[1];   // tensor_2 [256,256] f32
    // d_in[2] = rngSeq (arange) — folded into the unary-code identity.
    float* out = (float*)d_out;

    hipLaunchKernelGGL(scgemm_fused, dim3(256), dim3(1024), 0, stream, x1, x2, out);
}